// Round 7
// baseline (202.461 us; speedup 1.0000x reference)
//
#include <hip/hip_runtime.h>
#include <hip/hip_bf16.h>
#include <hip/hip_fp16.h>

typedef unsigned int   uint;
typedef unsigned short ushort;

#define NB   8
#define NC   64
#define LL   32768
#define KK   5
#define NG   4
#define NDG  2
#define NGD  8        // NG*NDG
#define NCD  8        // NC / NGD
#define NOFF 40       // NGD*KK
#define DWK  7
#define XROW (LL + 16)   // xT row stride in positions (8 guard slots each side)

typedef _Float16 f16x8 __attribute__((ext_vector_type(8)));
typedef float    f32x4 __attribute__((ext_vector_type(4)));

__device__ __forceinline__ uint pkrtz(float a, float b) {
  typedef __fp16 fp16x2n __attribute__((ext_vector_type(2)));
  fp16x2n h = __builtin_amdgcn_cvt_pkrtz(a, b);
  union { fp16x2n h; uint u; } v; v.h = h; return v.u;
}

// ---------------------------------------------------------------------------
// k_prep: wtA/wtM raw folded layouts + Wf (deform A-frags, verified layout).
// ---------------------------------------------------------------------------
__global__ __launch_bounds__(256) void k_prep(
    const float* __restrict__ pwA, const float* __restrict__ pwM,
    const float* __restrict__ mw,
    float* __restrict__ wtA, float* __restrict__ wtM, ushort* __restrict__ Wf)
{
  int idx = blockIdx.x * 256 + threadIdx.x;
  if (idx < 2560) {
    int c = idx / 40, o = idx % 40;
    wtA[idx] = pwA[o * NC + c];
  } else if (idx < 5120) {
    int j = idx - 2560;
    int c = j / 40, o = j % 40;
    wtM[j] = pwM[o * NC + c];
  } else if (idx < 11264) {
    int j  = idx - 5120;          // [0, 6144)
    int jj = j & 7;
    int l  = (j >> 3) & 63;
    int gt = j >> 9;              // [0,12)
    int t  = gt % 3, g = gt / 3;
    int o  = l & 15;
    int kq = t * 32 + ((l >> 4) << 3) + jj;
    float val = 0.f;
    if (kq < 80) {
      int ktap = kq >> 3, c = kq & 7;
      int d = ktap / 5, kh = ktap % 5;
      val = mw[((g * 16 + o) * 16 + d * 8 + c) * KK + kh];
    }
    Wf[j] = __half_as_ushort(__float2half(val));
  }
}

// ---------------------------------------------------------------------------
// k_stat: conv7 both branches for STATS ONLY (no y materialization: k_pd
// recomputes the conv bit-identically from x) + xT emit (raw x f16, gather
// layout with guards). 8 ch x 256 pos per block, grid 8192 (the R5 geometry
// that profiled at 58% occupancy). Traffic 139 -> ~72 MB vs old k_conv.
// ---------------------------------------------------------------------------
__device__ __forceinline__ void load8f(float* dst, const float* __restrict__ row,
                                       int start)
{
  if (start >= 0 && start + 8 <= LL) {
    float4 a = *(const float4*)(row + start);
    float4 b = *(const float4*)(row + start + 4);
    dst[0] = a.x; dst[1] = a.y; dst[2] = a.z; dst[3] = a.w;
    dst[4] = b.x; dst[5] = b.y; dst[6] = b.z; dst[7] = b.w;
  } else {
#pragma unroll
    for (int j = 0; j < 8; ++j) {
      int p = start + j;
      dst[j] = (p >= 0 && p < LL) ? row[p] : 0.f;
    }
  }
}

__global__ __launch_bounds__(256) void k_stat(
    const float* __restrict__ x,
    const float* __restrict__ dwAw, const float* __restrict__ dwAb,
    const float* __restrict__ dwMw, const float* __restrict__ dwMb,
    ushort* __restrict__ xT, float4* __restrict__ partial)
{
  __shared__ __align__(16) ushort lx[8 * 256];   // raw x f16 tile [c][pos]
  int tid  = threadIdx.x;
  int lblk = blockIdx.x & 127;
  int gd   = (blockIdx.x >> 7) & 7;
  int b    = blockIdx.x >> 10;
  int c    = tid >> 5;          // channel within gd group (0..7)
  int q    = tid & 31;          // 8-position chunk within 256
  int l0   = lblk << 8;
  int lb   = l0 + q * 8;
  int ch   = gd * 8 + c;
  const float* row = x + (size_t)(b * NC + ch) * LL;

  float v[24];
  load8f(v + 0,  row, lb - 8);
  load8f(v + 8,  row, lb);
  load8f(v + 16, row, lb + 8);

  {
    uint4 xr;
    xr.x = pkrtz(v[8],  v[9]);
    xr.y = pkrtz(v[10], v[11]);
    xr.z = pkrtz(v[12], v[13]);
    xr.w = pkrtz(v[14], v[15]);
    *(uint4*)(lx + c * 256 + q * 8) = xr;
  }

  float wa[DWK], wm[DWK];
#pragma unroll
  for (int j = 0; j < DWK; ++j) {
    wa[j] = dwAw[ch * DWK + j];
    wm[j] = dwMw[ch * DWK + j];
  }
  float ba = dwAb[ch], bm = dwMb[ch];

  float sa = 0.f, qa = 0.f, sm = 0.f, qm = 0.f;
#pragma unroll
  for (int u = 0; u < 8; ++u) {
    float ya = ba, ym = bm;
#pragma unroll
    for (int j = 0; j < DWK; ++j) {
      float xv = v[5 + u + j];  // x[lb+u-3+j]
      ya += wa[j] * xv;
      ym += wm[j] * xv;
    }
    sa += ya; qa += ya * ya;
    sm += ym; qm += ym * ym;
  }

  // butterfly reduce over the 32 lanes sharing this channel
#pragma unroll
  for (int m = 1; m < 32; m <<= 1) {
    sa += __shfl_xor(sa, m);
    qa += __shfl_xor(qa, m);
    sm += __shfl_xor(sm, m);
    qm += __shfl_xor(qm, m);
  }
  if (q == 0)
    partial[((size_t)(b * NC + ch) << 7) + lblk] = make_float4(sa, qa, sm, qm);

  __syncthreads();
  {
    uint4 pk;
    pk.x = (uint)lx[0 * 256 + tid] | ((uint)lx[1 * 256 + tid] << 16);
    pk.y = (uint)lx[2 * 256 + tid] | ((uint)lx[3 * 256 + tid] << 16);
    pk.z = (uint)lx[4 * 256 + tid] | ((uint)lx[5 * 256 + tid] << 16);
    pk.w = (uint)lx[6 * 256 + tid] | ((uint)lx[7 * 256 + tid] << 16);
    size_t rowbase = (size_t)(b * NGD + gd) * (size_t)XROW;
    *(uint4*)(xT + (rowbase + 8 + (size_t)(l0 + tid)) * 8) = pk;
    if (tid < 8) {
      uint4 z = {0, 0, 0, 0};
      if (lblk == 0)   *(uint4*)(xT + (rowbase + tid) * 8) = z;
      if (lblk == 127) *(uint4*)(xT + (rowbase + 8 + LL + tid) * 8) = z;
    }
  }
}

// ---------------------------------------------------------------------------
// k_fin: reduce the 128 per-chunk stat partials per channel, fold GN into
// pointwise weights, emit per-batch f16 A-frags with PER-GROUP m-tiles:
//   wFp[b][br][g][ks][lane][j] = fold(W)[c = ks*32+(lane>>4)*8+j][o = 10g+(lane&15)]
//   (rows (lane&15) >= 10 zero pad); biasPt[b][br][g][m].
// ---------------------------------------------------------------------------
__global__ __launch_bounds__(256) void k_fin(
    const float4* __restrict__ partial,
    const float* __restrict__ gnAw, const float* __restrict__ gnAb,
    const float* __restrict__ gnMw, const float* __restrict__ gnMb,
    const float* __restrict__ wtA, const float* __restrict__ wtM,
    const float* __restrict__ pbA, const float* __restrict__ pbM,
    ushort* __restrict__ wFp, float* __restrict__ biasPt)
{
  __shared__ float4 pr[256];
  __shared__ float gA[64], cA[64], gM[64], cM[64];
  __shared__ float sbA[40], sbM[40];
  int b = blockIdx.x;
  int t = threadIdx.x;
  {
    int c = t & 63, seg = t >> 6;
    const float4* pp = partial + ((size_t)(b * NC + c) << 7);
    float4 s = make_float4(0.f, 0.f, 0.f, 0.f);
    for (int i = seg; i < 128; i += 4) {
      float4 u = pp[i];
      s.x += u.x; s.y += u.y; s.z += u.z; s.w += u.w;
    }
    pr[t] = s;
  }
  __syncthreads();
  if (t < 64) {
    float4 a0 = pr[t], a1 = pr[t + 64], a2 = pr[t + 128], a3 = pr[t + 192];
    float sx = a0.x + a1.x + a2.x + a3.x;
    float sy = a0.y + a1.y + a2.y + a3.y;
    float sz = a0.z + a1.z + a2.z + a3.z;
    float sw = a0.w + a1.w + a2.w + a3.w;
    float mua = sx / LL, vara = sy / LL - mua * mua;
    float mum = sz / LL, varm = sw / LL - mum * mum;
    float ga = gnAw[t] * rsqrtf(vara + 1e-5f);
    float gm = gnMw[t] * rsqrtf(varm + 1e-5f);
    gA[t] = ga; cA[t] = gnAb[t] - mua * ga;
    gM[t] = gm; cM[t] = gnMb[t] - mum * gm;
  }
  __syncthreads();
  if (t < 40) {
    float sA = 0.f, sM = 0.f;
    for (int c = 0; c < 64; ++c) {
      sA += wtA[c * 40 + t] * cA[c];
      sM += wtM[c * 40 + t] * cM[c];
    }
    sbA[t] = 4.f * (pbA[t] + sA);
    sbM[t] = pbM[t] + sM;
  }
  // fragment weights (2 br x 4 g x 2 ks x 64 ln x 8 j = 8192)
  for (int idx = t; idx < 8192; idx += 256) {
    int br = idx >> 12;
    int e  = idx & 4095;
    int g  = e >> 10;
    int ks = (e >> 9) & 1;
    int ln = (e >> 3) & 63;
    int j  = e & 7;
    int rr = ln & 15;
    int c  = ks * 32 + ((ln >> 4) << 3) + j;
    float v = 0.f;
    if (rr < 10) {
      int o = 10 * g + rr;
      v = br ? wtM[c * 40 + o] * gM[c] : 4.f * wtA[c * 40 + o] * gA[c];
    }
    wFp[(size_t)b * 8192 + idx] = __half_as_ushort(__float2half(v));
  }
  __syncthreads();
  if (t < 128) {
    int br = t >> 6, g = (t >> 4) & 3, m = t & 15;
    float v = 0.f;
    if (m < 10) v = br ? sbM[10 * g + m] : sbA[10 * g + m];
    biasPt[b * 128 + t] = v;
  }
}

// ---------------------------------------------------------------------------
// k_pd: fused conv-recompute + pointwise + softmax + deform per 64-pos block.
// Phase 0 (conv staging): thread (c = tid>>2, q = tid&3) recomputes
//   h[c][q*16..+15] = conv7(x) with the EXACT k_stat FMA order (bit-identical
//   to the old yAM values), packs word = f16(hA)|f16(hM)<<16 into LDS at
//   byte c*256 + ((pos*4) ^ (hc(c)<<6) ^ ((c&3)<<4)), hc(c) = (c>>3)&3.
//   Swizzle derivation: write phase (16 lanes: c 0-3 x q 0-3, i fixed):
//   off mod 128 = (q&1)*64 + (i^(c&3))*16 -> 8 slots x 2 lanes = conflict-
//   free b128. Read instr j has c&3 = j&3 constant -> per-j constant XOR,
//   lane->bank map unchanged from the proven (h<<6)-only layout.
// Phase 1 (point): wave w computes channels 10w..10w+9 for all 64 pos.
// Handoff: dump (off,logit) to wave-private region, reread, f32 softmax.
// Phase 2 (deform): verified body, g = wave id.
// ---------------------------------------------------------------------------
__global__ __launch_bounds__(256) void k_pd(
    const float* __restrict__ x,
    const float* __restrict__ dwAw, const float* __restrict__ dwAb,
    const float* __restrict__ dwMw, const float* __restrict__ dwMb,
    const ushort* __restrict__ xT,
    const ushort* __restrict__ wFp, const float* __restrict__ biasPt,
    const ushort* __restrict__ Wf, const float* __restrict__ bias,
    float* __restrict__ out)
{
  __shared__ __align__(16) char S[4 * 12288];   // 48 KB
  int tid = threadIdx.x;
  int w   = tid >> 6;
  int ln  = tid & 63;
  int h   = ln >> 4;
  int col = ln & 15;
  int b   = blockIdx.x >> 9;
  int lb0 = (blockIdx.x & 511) << 6;

  // ---- phase 0: conv-recompute staging ----
  {
    int cc = tid >> 2;            // channel 0..63
    int q  = tid & 3;             // 16-pos chunk
    int p0 = lb0 + q * 16;
    const float* row = x + (size_t)(b * NC + cc) * LL;
    float v[32];
    load8f(v + 0,  row, p0 - 8);
    load8f(v + 8,  row, p0);
    load8f(v + 16, row, p0 + 8);
    load8f(v + 24, row, p0 + 16);
    float wa[DWK], wm[DWK];
#pragma unroll
    for (int j = 0; j < DWK; ++j) {
      wa[j] = dwAw[cc * DWK + j];
      wm[j] = dwMw[cc * DWK + j];
    }
    float ba = dwAb[cc], bm = dwMb[cc];
    uint wbuf[16];
#pragma unroll
    for (int u = 0; u < 16; ++u) {
      float ya = ba, ym = bm;
#pragma unroll
      for (int j = 0; j < DWK; ++j) {
        float xv = v[5 + u + j];  // x[p0+u-3+j]
        ya += wa[j] * xv;
        ym += wm[j] * xv;
      }
      wbuf[u] = pkrtz(ya, ym);
    }
    int hc = (cc >> 3) & 3;
    char* base = S + cc * 256;
    int xr = (hc << 6) ^ ((cc & 3) << 4);
#pragma unroll
    for (int i = 0; i < 4; ++i) {
      uint4 wv;
      wv.x = wbuf[i * 4 + 0]; wv.y = wbuf[i * 4 + 1];
      wv.z = wbuf[i * 4 + 2]; wv.w = wbuf[i * 4 + 3];
      *(uint4*)(base + ((q * 64 + i * 16) ^ xr)) = wv;
    }
  }

  // A-frags + bias (global loads overlap staging)
  const uint4* wFb = (const uint4*)(wFp + (size_t)b * 8192);
  f16x8 afA[2], afM[2];
#pragma unroll
  for (int ks = 0; ks < 2; ++ks) {
    union { uint4 u; f16x8 v; } cvA, cvM;
    cvA.u = wFb[(w * 2 + ks) * 64 + ln];
    cvM.u = wFb[512 + (w * 2 + ks) * 64 + ln];
    afA[ks] = cvA.v; afM[ks] = cvM.v;
  }
  f32x4 accA[4], accM[4];
  {
    float4 bvA = *(const float4*)(biasPt + b * 128 + w * 16 + h * 4);
    float4 bvM = *(const float4*)(biasPt + b * 128 + 64 + w * 16 + h * 4);
#pragma unroll
    for (int nt = 0; nt < 4; ++nt) {
      accA[nt][0]=bvA.x; accA[nt][1]=bvA.y; accA[nt][2]=bvA.z; accA[nt][3]=bvA.w;
      accM[nt][0]=bvM.x; accM[nt][1]=bvM.y; accM[nt][2]=bvM.z; accM[nt][3]=bvM.w;
    }
  }
  __syncthreads();

  // ---- phase 1: point MFMAs ----
  __builtin_amdgcn_s_setprio(1);
#pragma unroll
  for (int nt = 0; nt < 4; ++nt) {
#pragma unroll
    for (int ks = 0; ks < 2; ++ks) {
      const char* rowb = S + (ks * 32 + h * 8) * 256;
      int p4 = (((nt * 16 + col) << 2)) ^ (h << 6);
      uint r0 = *(const uint*)(rowb + 0 * 256 + (p4 ^ 0));
      uint r1 = *(const uint*)(rowb + 1 * 256 + (p4 ^ 16));
      uint r2 = *(const uint*)(rowb + 2 * 256 + (p4 ^ 32));
      uint r3 = *(const uint*)(rowb + 3 * 256 + (p4 ^ 48));
      uint r4 = *(const uint*)(rowb + 4 * 256 + (p4 ^ 0));
      uint r5 = *(const uint*)(rowb + 5 * 256 + (p4 ^ 16));
      uint r6 = *(const uint*)(rowb + 6 * 256 + (p4 ^ 32));
      uint r7 = *(const uint*)(rowb + 7 * 256 + (p4 ^ 48));
      union { uint u[4]; f16x8 v; } bA, bM;
      bA.u[0] = __builtin_amdgcn_perm(r1, r0, 0x05040100u);
      bA.u[1] = __builtin_amdgcn_perm(r3, r2, 0x05040100u);
      bA.u[2] = __builtin_amdgcn_perm(r5, r4, 0x05040100u);
      bA.u[3] = __builtin_amdgcn_perm(r7, r6, 0x05040100u);
      bM.u[0] = __builtin_amdgcn_perm(r1, r0, 0x07060302u);
      bM.u[1] = __builtin_amdgcn_perm(r3, r2, 0x07060302u);
      bM.u[2] = __builtin_amdgcn_perm(r5, r4, 0x07060302u);
      bM.u[3] = __builtin_amdgcn_perm(r7, r6, 0x07060302u);
      accA[nt] = __builtin_amdgcn_mfma_f32_16x16x32_f16(afA[ks], bA.v,
                                                        accA[nt], 0, 0, 0);
      accM[nt] = __builtin_amdgcn_mfma_f32_16x16x32_f16(afM[ks], bM.v,
                                                        accM[nt], 0, 0, 0);
    }
  }
  __builtin_amdgcn_s_setprio(0);
  __syncthreads();   // all waves done reading h before dumps overwrite it

  // ---- dump (off, logit) into wave-private region, reread per-position ----
  char* wb = S + w * 12288;
#pragma unroll
  for (int r = 0; r < 4; ++r) {
    int s = h * 4 + r;
    if (s < 10) {
#pragma unroll
      for (int nt = 0; nt < 4; ++nt) {
        int pos = nt * 16 + col;
        *(float*)(wb + (s << 8) + (pos << 2)) = accA[nt][r];
        *(float*)(wb + 2560 + (s << 8) + (pos << 2)) = accM[nt][r];
      }
    }
  }
  // same-wave DS ordering guarantees dump visibility for these reads
  float off[10], lg[10];
#pragma unroll
  for (int s = 0; s < 10; ++s) {
    off[s] = *(const float*)(wb + (s << 8) + (ln << 2));
    lg[s]  = *(const float*)(wb + 2560 + (s << 8) + (ln << 2));
  }
  // softmax per 5-tap group, f32 (lane-local)
  float at[10];
  {
    float m0 = fmaxf(fmaxf(fmaxf(lg[0], lg[1]), fmaxf(lg[2], lg[3])), lg[4]);
    float m1 = fmaxf(fmaxf(fmaxf(lg[5], lg[6]), fmaxf(lg[7], lg[8])), lg[9]);
    float e[10], s0 = 0.f, s1 = 0.f;
#pragma unroll
    for (int j = 0; j < 5; ++j) { e[j] = __expf(lg[j] - m0); s0 += e[j]; }
#pragma unroll
    for (int j = 5; j < 10; ++j) { e[j] = __expf(lg[j] - m1); s1 += e[j]; }
    float r0 = 1.f / s0, r1 = 1.f / s1;
#pragma unroll
    for (int j = 0; j < 5; ++j)  at[j] = e[j] * r0;
#pragma unroll
    for (int j = 5; j < 10; ++j) at[j] = e[j] * r1;
  }

  // ---- phase 2: deform, g = wave id, position l = lb0 + ln ----
  int g = w;
  int l = lb0 + ln;

  f16x8 af[3];
#pragma unroll
  for (int t = 0; t < 3; ++t) {
    union { uint4 u; f16x8 hh; } cv;
    cv.u = ((const uint4*)Wf)[(g * 3 + t) * 64 + ln];
    af[t] = cv.hh;
  }
  int orow = (ln >> 4) << 2;
  float4 b4 = *(const float4*)(bias + g * 16 + orow);
  f32x4 acc[4];
#pragma unroll
  for (int nb = 0; nb < 4; ++nb) {
    acc[nb][0] = b4.x; acc[nb][1] = b4.y; acc[nb][2] = b4.z; acc[nb][3] = b4.w;
  }

  char* sb  = wb;                   // wave-private S tile (overwrites dump)
  int nbase = ln * 192;             // 96 f16 per row
  int msk   = (ln & 7) << 4;

  // zero the K-pad (kidx 80..95) -- after the rereads above
  {
    f16x8 Z = {};
    *(f16x8*)(sb + ((nbase + 160) ^ msk)) = Z;
    *(f16x8*)(sb + ((nbase + 176) ^ msk)) = Z;
  }

#pragma unroll
  for (int d = 0; d < NDG; ++d) {
    const ushort* xr = xT + (size_t)(b * NGD + g * 2 + d) * (size_t)XROW * 8;
#pragma unroll
    for (int kh = 0; kh < KK; ++kh) {
      int s = d * KK + kh;
      float p = (float)(l - 2 + kh) + off[s];
      p = fminf(fmaxf(p, -1.f), 32768.f);
      float p0f = floorf(p);
      float w1  = p - p0f;
      int   i0  = (int)p0f;
      float f0 = (1.f - w1) * at[s];
      float f1 = w1 * at[s];
      _Float16 a0 = (_Float16)f0;
      _Float16 a1 = (_Float16)f1;
      f16x8 F0 = {a0, a0, a0, a0, a0, a0, a0, a0};
      f16x8 F1 = {a1, a1, a1, a1, a1, a1, a1, a1};
      const ushort* qp = xr + (size_t)(i0 + 8) * 8;
      f16x8 X0 = *(const f16x8*)qp;
      f16x8 X1 = *(const f16x8*)(qp + 8);
      f16x8 S8 = X0 * F0 + X1 * F1;
      *(f16x8*)(sb + ((nbase + s * 16) ^ msk)) = S8;
    }
  }

  int rb0 = (ln & 15) * 192 + ((ln >> 4) << 4);
  __builtin_amdgcn_s_setprio(1);
#pragma unroll
  for (int nb = 0; nb < 4; ++nb) {
#pragma unroll
    for (int t = 0; t < 3; ++t) {
      f16x8 bf = *(const f16x8*)(sb + ((rb0 + nb * 3072 + t * 64) ^ msk));
      acc[nb] = __builtin_amdgcn_mfma_f32_16x16x32_f16(af[t], bf, acc[nb],
                                                       0, 0, 0);
    }
  }
  __builtin_amdgcn_s_setprio(0);

  float* ob = out + (size_t)(b * NC + g * 16 + orow) * LL + lb0 + (ln & 15);
#pragma unroll
  for (int nb = 0; nb < 4; ++nb) {
#pragma unroll
    for (int r = 0; r < 4; ++r)
      ob[(size_t)r * LL + (nb << 4)] = acc[nb][r];
  }
}

// ---------------------------------------------------------------------------
extern "C" void kernel_launch(void* const* d_in, const int* in_sizes, int n_in,
                              void* d_out, int out_size, void* d_ws, size_t ws_size,
                              hipStream_t stream)
{
  const float* x    = (const float*)d_in[0];
  const float* dwAw = (const float*)d_in[1];
  const float* dwAb = (const float*)d_in[2];
  const float* gnAw = (const float*)d_in[3];
  const float* gnAb = (const float*)d_in[4];
  const float* pwAw = (const float*)d_in[5];
  const float* pwAb = (const float*)d_in[6];
  const float* dwMw = (const float*)d_in[7];
  const float* dwMb = (const float*)d_in[8];
  const float* gnMw = (const float*)d_in[9];
  const float* gnMb = (const float*)d_in[10];
  const float* pwMw = (const float*)d_in[11];
  const float* pwMb = (const float*)d_in[12];
  const float* mw   = (const float*)d_in[13];
  const float* bias = (const float*)d_in[14];
  float* out = (float*)d_out;

  // Workspace (~36 MB total; yAM eliminated):
  float* wtA = (float*)d_ws;                       // 2560 f
  float* wtM = wtA + 2560;                         // 2560 f
  ushort* Wf = (ushort*)(wtM + 2560);              // 6144 us
  ushort* wFp = Wf + 6144;                         // 8*8192 us (128 KB)
  float* biasPt = (float*)(wFp + 65536);           // 8*128 f
  float4* partial = (float4*)(biasPt + 1024);      // 64K float4 (1 MB)
  ushort* xT = (ushort*)(partial + 65536);         // 16.79M us (33.6 MB)

  hipLaunchKernelGGL(k_prep, dim3(44), dim3(256), 0, stream,
                     pwAw, pwMw, mw, wtA, wtM, Wf);
  hipLaunchKernelGGL(k_stat, dim3(NB * NGD * 128), dim3(256), 0, stream,
                     x, dwAw, dwAb, dwMw, dwMb, xT, partial);
  hipLaunchKernelGGL(k_fin, dim3(NB), dim3(256), 0, stream,
                     partial, gnAw, gnAb, gnMw, gnMb, wtA, wtM, pwAb, pwMb,
                     wFp, biasPt);
  hipLaunchKernelGGL(k_pd, dim3(NB * 512), dim3(256), 0, stream,
                     x, dwAw, dwAb, dwMw, dwMb, xT, wFp, biasPt, Wf, bias, out);
}

// Round 8
// 199.454 us; speedup vs baseline: 1.0151x; 1.0151x over previous
//
#include <hip/hip_runtime.h>
#include <hip/hip_bf16.h>
#include <hip/hip_fp16.h>

typedef unsigned int   uint;
typedef unsigned short ushort;

#define NB   8
#define NC   64
#define LL   32768
#define KK   5
#define NG   4
#define NDG  2
#define NGD  8        // NG*NDG
#define NCD  8        // NC / NGD
#define NOFF 40       // NGD*KK
#define DWK  7
#define XROW (LL + 16)   // xT row stride in positions (8 guard slots each side)

typedef _Float16 f16x8 __attribute__((ext_vector_type(8)));
typedef float    f32x4 __attribute__((ext_vector_type(4)));

__device__ __forceinline__ uint pkrtz(float a, float b) {
  typedef __fp16 fp16x2n __attribute__((ext_vector_type(2)));
  fp16x2n h = __builtin_amdgcn_cvt_pkrtz(a, b);
  union { fp16x2n h; uint u; } v; v.h = h; return v.u;
}

// ---------------------------------------------------------------------------
// k_prep: wtA/wtM raw folded layouts + Wf (deform A-frags, verified layout).
// ---------------------------------------------------------------------------
__global__ __launch_bounds__(256) void k_prep(
    const float* __restrict__ pwA, const float* __restrict__ pwM,
    const float* __restrict__ mw,
    float* __restrict__ wtA, float* __restrict__ wtM, ushort* __restrict__ Wf)
{
  int idx = blockIdx.x * 256 + threadIdx.x;
  if (idx < 2560) {
    int c = idx / 40, o = idx % 40;
    wtA[idx] = pwA[o * NC + c];
  } else if (idx < 5120) {
    int j = idx - 2560;
    int c = j / 40, o = j % 40;
    wtM[j] = pwM[o * NC + c];
  } else if (idx < 11264) {
    int j  = idx - 5120;          // [0, 6144)
    int jj = j & 7;
    int l  = (j >> 3) & 63;
    int gt = j >> 9;              // [0,12)
    int t  = gt % 3, g = gt / 3;
    int o  = l & 15;
    int kq = t * 32 + ((l >> 4) << 3) + jj;
    float val = 0.f;
    if (kq < 80) {
      int ktap = kq >> 3, c = kq & 7;
      int d = ktap / 5, kh = ktap % 5;
      val = mw[((g * 16 + o) * 16 + d * 8 + c) * KK + kh];
    }
    Wf[j] = __half_as_ushort(__float2half(val));
  }
}

// ---------------------------------------------------------------------------
// k_stat: conv7 both branches for STATS ONLY (k_pd recomputes the conv bit-
// identically from x) + xT emit (raw x f16, gather layout with guards).
// 8 ch x 256 pos per block, grid 8192.
// ---------------------------------------------------------------------------
__device__ __forceinline__ void load8f(float* dst, const float* __restrict__ row,
                                       int start)
{
  if (start >= 0 && start + 8 <= LL) {
    float4 a = *(const float4*)(row + start);
    float4 b = *(const float4*)(row + start + 4);
    dst[0] = a.x; dst[1] = a.y; dst[2] = a.z; dst[3] = a.w;
    dst[4] = b.x; dst[5] = b.y; dst[6] = b.z; dst[7] = b.w;
  } else {
#pragma unroll
    for (int j = 0; j < 8; ++j) {
      int p = start + j;
      dst[j] = (p >= 0 && p < LL) ? row[p] : 0.f;
    }
  }
}

__global__ __launch_bounds__(256) void k_stat(
    const float* __restrict__ x,
    const float* __restrict__ dwAw, const float* __restrict__ dwAb,
    const float* __restrict__ dwMw, const float* __restrict__ dwMb,
    ushort* __restrict__ xT, float4* __restrict__ partial)
{
  __shared__ __align__(16) ushort lx[8 * 256];   // raw x f16 tile [c][pos]
  int tid  = threadIdx.x;
  int lblk = blockIdx.x & 127;
  int gd   = (blockIdx.x >> 7) & 7;
  int b    = blockIdx.x >> 10;
  int c    = tid >> 5;          // channel within gd group (0..7)
  int q    = tid & 31;          // 8-position chunk within 256
  int l0   = lblk << 8;
  int lb   = l0 + q * 8;
  int ch   = gd * 8 + c;
  const float* row = x + (size_t)(b * NC + ch) * LL;

  float v[24];
  load8f(v + 0,  row, lb - 8);
  load8f(v + 8,  row, lb);
  load8f(v + 16, row, lb + 8);

  {
    uint4 xr;
    xr.x = pkrtz(v[8],  v[9]);
    xr.y = pkrtz(v[10], v[11]);
    xr.z = pkrtz(v[12], v[13]);
    xr.w = pkrtz(v[14], v[15]);
    *(uint4*)(lx + c * 256 + q * 8) = xr;
  }

  float wa[DWK], wm[DWK];
#pragma unroll
  for (int j = 0; j < DWK; ++j) {
    wa[j] = dwAw[ch * DWK + j];
    wm[j] = dwMw[ch * DWK + j];
  }
  float ba = dwAb[ch], bm = dwMb[ch];

  float sa = 0.f, qa = 0.f, sm = 0.f, qm = 0.f;
#pragma unroll
  for (int u = 0; u < 8; ++u) {
    float ya = ba, ym = bm;
#pragma unroll
    for (int j = 0; j < DWK; ++j) {
      float xv = v[5 + u + j];  // x[lb+u-3+j]
      ya += wa[j] * xv;
      ym += wm[j] * xv;
    }
    sa += ya; qa += ya * ya;
    sm += ym; qm += ym * ym;
  }

  // butterfly reduce over the 32 lanes sharing this channel
#pragma unroll
  for (int m = 1; m < 32; m <<= 1) {
    sa += __shfl_xor(sa, m);
    qa += __shfl_xor(qa, m);
    sm += __shfl_xor(sm, m);
    qm += __shfl_xor(qm, m);
  }
  if (q == 0)
    partial[((size_t)(b * NC + ch) << 7) + lblk] = make_float4(sa, qa, sm, qm);

  __syncthreads();
  {
    uint4 pk;
    pk.x = (uint)lx[0 * 256 + tid] | ((uint)lx[1 * 256 + tid] << 16);
    pk.y = (uint)lx[2 * 256 + tid] | ((uint)lx[3 * 256 + tid] << 16);
    pk.z = (uint)lx[4 * 256 + tid] | ((uint)lx[5 * 256 + tid] << 16);
    pk.w = (uint)lx[6 * 256 + tid] | ((uint)lx[7 * 256 + tid] << 16);
    size_t rowbase = (size_t)(b * NGD + gd) * (size_t)XROW;
    *(uint4*)(xT + (rowbase + 8 + (size_t)(l0 + tid)) * 8) = pk;
    if (tid < 8) {
      uint4 z = {0, 0, 0, 0};
      if (lblk == 0)   *(uint4*)(xT + (rowbase + tid) * 8) = z;
      if (lblk == 127) *(uint4*)(xT + (rowbase + 8 + LL + tid) * 8) = z;
    }
  }
}

// ---------------------------------------------------------------------------
// k_fin: reduce the 128 per-chunk stat partials per channel, fold GN into
// pointwise weights, emit per-batch f16 A-frags with PER-GROUP m-tiles:
//   wFp[b][br][g][ks][lane][j] = fold(W)[c = ks*32+(lane>>4)*8+j][o = 10g+(lane&15)]
//   (rows (lane&15) >= 10 zero pad); biasPt[b][br][g][m].
// ---------------------------------------------------------------------------
__global__ __launch_bounds__(256) void k_fin(
    const float4* __restrict__ partial,
    const float* __restrict__ gnAw, const float* __restrict__ gnAb,
    const float* __restrict__ gnMw, const float* __restrict__ gnMb,
    const float* __restrict__ wtA, const float* __restrict__ wtM,
    const float* __restrict__ pbA, const float* __restrict__ pbM,
    ushort* __restrict__ wFp, float* __restrict__ biasPt)
{
  __shared__ float4 pr[256];
  __shared__ float gA[64], cA[64], gM[64], cM[64];
  __shared__ float sbA[40], sbM[40];
  int b = blockIdx.x;
  int t = threadIdx.x;
  {
    int c = t & 63, seg = t >> 6;
    const float4* pp = partial + ((size_t)(b * NC + c) << 7);
    float4 s = make_float4(0.f, 0.f, 0.f, 0.f);
    for (int i = seg; i < 128; i += 4) {
      float4 u = pp[i];
      s.x += u.x; s.y += u.y; s.z += u.z; s.w += u.w;
    }
    pr[t] = s;
  }
  __syncthreads();
  if (t < 64) {
    float4 a0 = pr[t], a1 = pr[t + 64], a2 = pr[t + 128], a3 = pr[t + 192];
    float sx = a0.x + a1.x + a2.x + a3.x;
    float sy = a0.y + a1.y + a2.y + a3.y;
    float sz = a0.z + a1.z + a2.z + a3.z;
    float sw = a0.w + a1.w + a2.w + a3.w;
    float mua = sx / LL, vara = sy / LL - mua * mua;
    float mum = sz / LL, varm = sw / LL - mum * mum;
    float ga = gnAw[t] * rsqrtf(vara + 1e-5f);
    float gm = gnMw[t] * rsqrtf(varm + 1e-5f);
    gA[t] = ga; cA[t] = gnAb[t] - mua * ga;
    gM[t] = gm; cM[t] = gnMb[t] - mum * gm;
  }
  __syncthreads();
  if (t < 40) {
    float sA = 0.f, sM = 0.f;
    for (int c = 0; c < 64; ++c) {
      sA += wtA[c * 40 + t] * cA[c];
      sM += wtM[c * 40 + t] * cM[c];
    }
    sbA[t] = 4.f * (pbA[t] + sA);
    sbM[t] = pbM[t] + sM;
  }
  // fragment weights (2 br x 4 g x 2 ks x 64 ln x 8 j = 8192)
  for (int idx = t; idx < 8192; idx += 256) {
    int br = idx >> 12;
    int e  = idx & 4095;
    int g  = e >> 10;
    int ks = (e >> 9) & 1;
    int ln = (e >> 3) & 63;
    int j  = e & 7;
    int rr = ln & 15;
    int c  = ks * 32 + ((ln >> 4) << 3) + j;
    float v = 0.f;
    if (rr < 10) {
      int o = 10 * g + rr;
      v = br ? wtM[c * 40 + o] * gM[c] : 4.f * wtA[c * 40 + o] * gA[c];
    }
    wFp[(size_t)b * 8192 + idx] = __half_as_ushort(__float2half(v));
  }
  __syncthreads();
  if (t < 128) {
    int br = t >> 6, g = (t >> 4) & 3, m = t & 15;
    float v = 0.f;
    if (m < 10) v = br ? sbM[10 * g + m] : sbA[10 * g + m];
    biasPt[b * 128 + t] = v;
  }
}

// ---------------------------------------------------------------------------
// k_pd: fused conv-recompute + pointwise + softmax + deform per 64-pos block.
// LDS now 20 KB (was 48): the deform S-tile is STREAMED per K-step (32 kidx
// slice = 64 rows x 80 B pad-stride buffer, 5 KB/wave, exactly reusing the
// dump region) instead of fully materialized (12 KB/wave).
// Stride-80 derivation: row base mod 128 = 80n mod 128 cycles through all 8
// 16B slots every 8 rows -> b128 writes (lane n at n*80+sl*16) and reads
// (row nb*16+(ln&15), slot ln>>4) are uniformly bank-spread, no XOR needed.
// Numerics: identical ops in identical order vs R7 -> absmax bit-identical.
// ---------------------------------------------------------------------------
__global__ __launch_bounds__(256) void k_pd(
    const float* __restrict__ x,
    const float* __restrict__ dwAw, const float* __restrict__ dwAb,
    const float* __restrict__ dwMw, const float* __restrict__ dwMb,
    const ushort* __restrict__ xT,
    const ushort* __restrict__ wFp, const float* __restrict__ biasPt,
    const ushort* __restrict__ Wf, const float* __restrict__ bias,
    float* __restrict__ out)
{
  __shared__ __align__(16) char S[20480];   // 20 KB total
  int tid = threadIdx.x;
  int w   = tid >> 6;
  int ln  = tid & 63;
  int h   = ln >> 4;
  int col = ln & 15;
  int b   = blockIdx.x >> 9;
  int lb0 = (blockIdx.x & 511) << 6;

  // ---- phase 0: conv-recompute staging ----
  {
    int cc = tid >> 2;            // channel 0..63
    int q  = tid & 3;             // 16-pos chunk
    int p0 = lb0 + q * 16;
    const float* row = x + (size_t)(b * NC + cc) * LL;
    float v[32];
    load8f(v + 0,  row, p0 - 8);
    load8f(v + 8,  row, p0);
    load8f(v + 16, row, p0 + 8);
    load8f(v + 24, row, p0 + 16);
    float wa[DWK], wm[DWK];
#pragma unroll
    for (int j = 0; j < DWK; ++j) {
      wa[j] = dwAw[cc * DWK + j];
      wm[j] = dwMw[cc * DWK + j];
    }
    float ba = dwAb[cc], bm = dwMb[cc];
    uint wbuf[16];
#pragma unroll
    for (int u = 0; u < 16; ++u) {
      float ya = ba, ym = bm;
#pragma unroll
      for (int j = 0; j < DWK; ++j) {
        float xv = v[5 + u + j];  // x[p0+u-3+j]
        ya += wa[j] * xv;
        ym += wm[j] * xv;
      }
      wbuf[u] = pkrtz(ya, ym);
    }
    int hc = (cc >> 3) & 3;
    char* base = S + cc * 256;
    int xr = (hc << 6) ^ ((cc & 3) << 4);
#pragma unroll
    for (int i = 0; i < 4; ++i) {
      uint4 wv;
      wv.x = wbuf[i * 4 + 0]; wv.y = wbuf[i * 4 + 1];
      wv.z = wbuf[i * 4 + 2]; wv.w = wbuf[i * 4 + 3];
      *(uint4*)(base + ((q * 64 + i * 16) ^ xr)) = wv;
    }
  }

  // A-frags + bias (global loads overlap staging)
  const uint4* wFb = (const uint4*)(wFp + (size_t)b * 8192);
  f16x8 afA[2], afM[2];
#pragma unroll
  for (int ks = 0; ks < 2; ++ks) {
    union { uint4 u; f16x8 v; } cvA, cvM;
    cvA.u = wFb[(w * 2 + ks) * 64 + ln];
    cvM.u = wFb[512 + (w * 2 + ks) * 64 + ln];
    afA[ks] = cvA.v; afM[ks] = cvM.v;
  }
  f32x4 accA[4], accM[4];
  {
    float4 bvA = *(const float4*)(biasPt + b * 128 + w * 16 + h * 4);
    float4 bvM = *(const float4*)(biasPt + b * 128 + 64 + w * 16 + h * 4);
#pragma unroll
    for (int nt = 0; nt < 4; ++nt) {
      accA[nt][0]=bvA.x; accA[nt][1]=bvA.y; accA[nt][2]=bvA.z; accA[nt][3]=bvA.w;
      accM[nt][0]=bvM.x; accM[nt][1]=bvM.y; accM[nt][2]=bvM.z; accM[nt][3]=bvM.w;
    }
  }
  __syncthreads();

  // ---- phase 1: point MFMAs ----
  __builtin_amdgcn_s_setprio(1);
#pragma unroll
  for (int nt = 0; nt < 4; ++nt) {
#pragma unroll
    for (int ks = 0; ks < 2; ++ks) {
      const char* rowb = S + (ks * 32 + h * 8) * 256;
      int p4 = (((nt * 16 + col) << 2)) ^ (h << 6);
      uint r0 = *(const uint*)(rowb + 0 * 256 + (p4 ^ 0));
      uint r1 = *(const uint*)(rowb + 1 * 256 + (p4 ^ 16));
      uint r2 = *(const uint*)(rowb + 2 * 256 + (p4 ^ 32));
      uint r3 = *(const uint*)(rowb + 3 * 256 + (p4 ^ 48));
      uint r4 = *(const uint*)(rowb + 4 * 256 + (p4 ^ 0));
      uint r5 = *(const uint*)(rowb + 5 * 256 + (p4 ^ 16));
      uint r6 = *(const uint*)(rowb + 6 * 256 + (p4 ^ 32));
      uint r7 = *(const uint*)(rowb + 7 * 256 + (p4 ^ 48));
      union { uint u[4]; f16x8 v; } bA, bM;
      bA.u[0] = __builtin_amdgcn_perm(r1, r0, 0x05040100u);
      bA.u[1] = __builtin_amdgcn_perm(r3, r2, 0x05040100u);
      bA.u[2] = __builtin_amdgcn_perm(r5, r4, 0x05040100u);
      bA.u[3] = __builtin_amdgcn_perm(r7, r6, 0x05040100u);
      bM.u[0] = __builtin_amdgcn_perm(r1, r0, 0x07060302u);
      bM.u[1] = __builtin_amdgcn_perm(r3, r2, 0x07060302u);
      bM.u[2] = __builtin_amdgcn_perm(r5, r4, 0x07060302u);
      bM.u[3] = __builtin_amdgcn_perm(r7, r6, 0x07060302u);
      accA[nt] = __builtin_amdgcn_mfma_f32_16x16x32_f16(afA[ks], bA.v,
                                                        accA[nt], 0, 0, 0);
      accM[nt] = __builtin_amdgcn_mfma_f32_16x16x32_f16(afM[ks], bM.v,
                                                        accM[nt], 0, 0, 0);
    }
  }
  __builtin_amdgcn_s_setprio(0);
  __syncthreads();   // all waves done reading h before dumps overwrite it

  // ---- dump (off, logit) into wave-private 5 KB region, reread ----
  char* wb = S + w * 5120;
#pragma unroll
  for (int r = 0; r < 4; ++r) {
    int s = h * 4 + r;
    if (s < 10) {
#pragma unroll
      for (int nt = 0; nt < 4; ++nt) {
        int pos = nt * 16 + col;
        *(float*)(wb + (s << 8) + (pos << 2)) = accA[nt][r];
        *(float*)(wb + 2560 + (s << 8) + (pos << 2)) = accM[nt][r];
      }
    }
  }
  // same-wave DS ordering guarantees dump visibility for these reads
  float off[10], lg[10];
#pragma unroll
  for (int s = 0; s < 10; ++s) {
    off[s] = *(const float*)(wb + (s << 8) + (ln << 2));
    lg[s]  = *(const float*)(wb + 2560 + (s << 8) + (ln << 2));
  }
  // softmax per 5-tap group, f32 (lane-local)
  float at[10];
  {
    float m0 = fmaxf(fmaxf(fmaxf(lg[0], lg[1]), fmaxf(lg[2], lg[3])), lg[4]);
    float m1 = fmaxf(fmaxf(fmaxf(lg[5], lg[6]), fmaxf(lg[7], lg[8])), lg[9]);
    float e[10], s0 = 0.f, s1 = 0.f;
#pragma unroll
    for (int j = 0; j < 5; ++j) { e[j] = __expf(lg[j] - m0); s0 += e[j]; }
#pragma unroll
    for (int j = 5; j < 10; ++j) { e[j] = __expf(lg[j] - m1); s1 += e[j]; }
    float r0 = 1.f / s0, r1 = 1.f / s1;
#pragma unroll
    for (int j = 0; j < 5; ++j)  at[j] = e[j] * r0;
#pragma unroll
    for (int j = 5; j < 10; ++j) at[j] = e[j] * r1;
  }

  // ---- phase 2: deform with STREAMED K-step S-slices ----
  int g = w;
  int l = lb0 + ln;

  f16x8 af[3];
#pragma unroll
  for (int t = 0; t < 3; ++t) {
    union { uint4 u; f16x8 hh; } cv;
    cv.u = ((const uint4*)Wf)[(g * 3 + t) * 64 + ln];
    af[t] = cv.hh;
  }
  int orow = (ln >> 4) << 2;
  float4 b4 = *(const float4*)(bias + g * 16 + orow);
  f32x4 acc[4];
#pragma unroll
  for (int nb = 0; nb < 4; ++nb) {
    acc[nb][0] = b4.x; acc[nb][1] = b4.y; acc[nb][2] = b4.z; acc[nb][3] = b4.w;
  }

  // stream buffer = the dump region (rereads above complete first; same-wave
  // DS ops execute in program order, and aliasing prevents compiler reorder)
  char* buf = wb;                      // [64 rows][80 B] per wave
  int rbase = ((ln & 15)) * 80 + ((ln >> 4) << 4);
#pragma unroll
  for (int t = 0; t < 3; ++t) {
#pragma unroll
    for (int sl = 0; sl < 4; ++sl) {
      int s = 4 * t + sl;
      char* dst = buf + ln * 80 + sl * 16;
      if (s < 10) {
        const ushort* xr = xT + (size_t)(b * NGD + g * 2 + (s >= KK ? 1 : 0))
                                * (size_t)XROW * 8;
        int kh = s >= KK ? s - KK : s;
        float p = (float)(l - 2 + kh) + off[s];
        p = fminf(fmaxf(p, -1.f), 32768.f);
        float p0f = floorf(p);
        float w1  = p - p0f;
        int   i0  = (int)p0f;
        float f0 = (1.f - w1) * at[s];
        float f1 = w1 * at[s];
        _Float16 a0 = (_Float16)f0;
        _Float16 a1 = (_Float16)f1;
        f16x8 F0 = {a0, a0, a0, a0, a0, a0, a0, a0};
        f16x8 F1 = {a1, a1, a1, a1, a1, a1, a1, a1};
        const ushort* qp = xr + (size_t)(i0 + 8) * 8;
        f16x8 X0 = *(const f16x8*)qp;
        f16x8 X1 = *(const f16x8*)(qp + 8);
        f16x8 S8 = X0 * F0 + X1 * F1;
        *(f16x8*)dst = S8;
      } else {
        f16x8 Z = {};
        *(f16x8*)dst = Z;
      }
    }
    __builtin_amdgcn_s_setprio(1);
#pragma unroll
    for (int nb = 0; nb < 4; ++nb) {
      f16x8 bf = *(const f16x8*)(buf + nb * 16 * 80 + rbase);
      acc[nb] = __builtin_amdgcn_mfma_f32_16x16x32_f16(af[t], bf, acc[nb],
                                                       0, 0, 0);
    }
    __builtin_amdgcn_s_setprio(0);
  }

  float* ob = out + (size_t)(b * NC + g * 16 + orow) * LL + lb0 + (ln & 15);
#pragma unroll
  for (int nb = 0; nb < 4; ++nb) {
#pragma unroll
    for (int r = 0; r < 4; ++r)
      ob[(size_t)r * LL + (nb << 4)] = acc[nb][r];
  }
}

// ---------------------------------------------------------------------------
extern "C" void kernel_launch(void* const* d_in, const int* in_sizes, int n_in,
                              void* d_out, int out_size, void* d_ws, size_t ws_size,
                              hipStream_t stream)
{
  const float* x    = (const float*)d_in[0];
  const float* dwAw = (const float*)d_in[1];
  const float* dwAb = (const float*)d_in[2];
  const float* gnAw = (const float*)d_in[3];
  const float* gnAb = (const float*)d_in[4];
  const float* pwAw = (const float*)d_in[5];
  const float* pwAb = (const float*)d_in[6];
  const float* dwMw = (const float*)d_in[7];
  const float* dwMb = (const float*)d_in[8];
  const float* gnMw = (const float*)d_in[9];
  const float* gnMb = (const float*)d_in[10];
  const float* pwMw = (const float*)d_in[11];
  const float* pwMb = (const float*)d_in[12];
  const float* mw   = (const float*)d_in[13];
  const float* bias = (const float*)d_in[14];
  float* out = (float*)d_out;

  // Workspace (~36 MB total):
  float* wtA = (float*)d_ws;                       // 2560 f
  float* wtM = wtA + 2560;                         // 2560 f
  ushort* Wf = (ushort*)(wtM + 2560);              // 6144 us
  ushort* wFp = Wf + 6144;                         // 8*8192 us (128 KB)
  float* biasPt = (float*)(wFp + 65536);           // 8*128 f
  float4* partial = (float4*)(biasPt + 1024);      // 64K float4 (1 MB)
  ushort* xT = (ushort*)(partial + 65536);         // 16.79M us (33.6 MB)

  hipLaunchKernelGGL(k_prep, dim3(44), dim3(256), 0, stream,
                     pwAw, pwMw, mw, wtA, wtM, Wf);
  hipLaunchKernelGGL(k_stat, dim3(NB * NGD * 128), dim3(256), 0, stream,
                     x, dwAw, dwAb, dwMw, dwMb, xT, partial);
  hipLaunchKernelGGL(k_fin, dim3(NB), dim3(256), 0, stream,
                     partial, gnAw, gnAb, gnMw, gnMb, wtA, wtM, pwAb, pwMb,
                     wFp, biasPt);
  hipLaunchKernelGGL(k_pd, dim3(NB * 512), dim3(256), 0, stream,
                     x, dwAw, dwAb, dwMw, dwMb, xT, wFp, biasPt, Wf, bias, out);
}